// Round 1
// baseline (141.044 us; speedup 1.0000x reference)
//
#include <hip/hip_runtime.h>

// Problem: B=8, Na=Nb=4096, D=64. For each a-point: top-3 nearest b-points by
// quantized integer coords (>>4, values in [0,128)), weights 0.5-min(dist,0.5),
// weighted gather of b_feats, concat [a_feats | gathered] -> (B,Na,128) fp32.
//
// Key insight: d2 = |ca-cb|^2 is an exact integer < 2^16; sqrt is monotone and
// injective on these integers in fp32, so reference top-k ordering == integer
// d2 ordering with lowest-index tie-break. Selection done entirely on packed
// integer keys: key = (d2<<12)|idx  (idx<4096), min-3 == reference selection
// exactly (including ties).

#define NA 4096
#define NB 4096
#define FD 64
#define WPB 8                 // waves per block (a-points per block)
#define BLOCK (WPB * 64)

__global__ __launch_bounds__(BLOCK) void knn_gather_kernel(
    const float* __restrict__ a_feats,   // (B, NA, 64)
    const float* __restrict__ b_feats,   // (B, NB, 64)
    const int*   __restrict__ a_coords,  // (B, NA, 3)
    const int*   __restrict__ b_coords,  // (B, NB, 3)
    float* __restrict__ out)             // (B, NA, 128)
{
    __shared__ unsigned int sc[NB];      // packed b coords: x | y<<7 | z<<14

    const int batch = blockIdx.y;
    const int tid   = threadIdx.x;

    // ---- stage packed b coords into LDS (16 KB) ----
    const int* bc = b_coords + (size_t)batch * NB * 3;
    for (int i = tid; i < NB; i += BLOCK) {
        const int x = bc[3 * i + 0] >> 4;   // coords nonneg -> //16 == >>4
        const int y = bc[3 * i + 1] >> 4;
        const int z = bc[3 * i + 2] >> 4;
        sc[i] = (unsigned)(x | (y << 7) | (z << 14));
    }
    __syncthreads();

    const int wave = tid >> 6;
    const int lane = tid & 63;
    const int n    = blockIdx.x * WPB + wave;          // a-point index

    const int* ac = a_coords + ((size_t)batch * NA + n) * 3;
    const int ax = ac[0] >> 4;
    const int ay = ac[1] >> 4;
    const int az = ac[2] >> 4;

    // sorted local top-3 keys (k0 <= k1 <= k2)
    unsigned k0 = 0xFFFFFFFFu, k1 = 0xFFFFFFFFu, k2 = 0xFFFFFFFFu;

    // each lane scans 64 b-points: uint4 at [lane + 64*k] -> points 4*that+0..3
    const uint4* sc4 = (const uint4*)sc;
#pragma unroll 4
    for (int k = 0; k < 16; ++k) {
        const int q = lane + (k << 6);
        const uint4 p = sc4[q];            // conflict-free: lane i at 16B*i
        const unsigned mb = (unsigned)(q << 2);

#define KNN_INSERT(PW, M)                                            \
        {                                                            \
            const int dx = ax - (int)((PW) & 127u);                  \
            const int dy = ay - (int)(((PW) >> 7) & 127u);           \
            const int dz = az - (int)(((PW) >> 14) & 127u);          \
            const unsigned d2 = (unsigned)(dx*dx + dy*dy + dz*dz);   \
            const unsigned key = (d2 << 12) | (M);                   \
            const unsigned t = max(k0, key); k0 = min(k0, key);      \
            const unsigned u = max(k1, t);   k1 = min(k1, t);        \
            k2 = min(k2, u);                                         \
        }

        KNN_INSERT(p.x, mb + 0u)
        KNN_INSERT(p.y, mb + 1u)
        KNN_INSERT(p.z, mb + 2u)
        KNN_INSERT(p.w, mb + 3u)
#undef KNN_INSERT
    }

    // ---- butterfly merge of sorted triples across the 64 lanes ----
    // merge(A,B): out0=min(A0,B0); out1=min(max(A0,B0),min(A1,B1));
    //             out2=min(min(A2,B2), max(min(A1,B1), max(A0,B0)))
#pragma unroll
    for (int m = 1; m < 64; m <<= 1) {
        const unsigned b0 = (unsigned)__shfl_xor((int)k0, m, 64);
        const unsigned b1 = (unsigned)__shfl_xor((int)k1, m, 64);
        const unsigned b2 = (unsigned)__shfl_xor((int)k2, m, 64);
        const unsigned hi0 = max(k0, b0);
        const unsigned lo1 = min(k1, b1);
        const unsigned lo2 = min(k2, b2);
        k0 = min(k0, b0);
        k1 = min(hi0, lo1);
        k2 = min(lo2, max(lo1, hi0));
    }
    // all lanes now hold the global top-3 (sorted, ties -> lower index)

    const unsigned i0 = k0 & 4095u;
    const unsigned i1 = k1 & 4095u;
    const unsigned i2 = k2 & 4095u;
    const float d0 = sqrtf((float)(k0 >> 12)) * (1.0f / 128.0f);
    const float d1 = sqrtf((float)(k1 >> 12)) * (1.0f / 128.0f);
    const float d2f = sqrtf((float)(k2 >> 12)) * (1.0f / 128.0f);
    const float w0 = 0.5f - fminf(d0, 0.5f);
    const float w1 = 0.5f - fminf(d1, 0.5f);
    const float w2 = 0.5f - fminf(d2f, 0.5f);

    // ---- coalesced epilogue: lane = feature dim ----
    const float* bfb = b_feats + (size_t)batch * NB * FD;
    const size_t row = (size_t)batch * NA + n;

    const float g = w0 * bfb[i0 * FD + lane]
                  + w1 * bfb[i1 * FD + lane]
                  + w2 * bfb[i2 * FD + lane];

    out[row * 128 + lane]      = a_feats[row * FD + lane];
    out[row * 128 + 64 + lane] = g;
}

extern "C" void kernel_launch(void* const* d_in, const int* in_sizes, int n_in,
                              void* d_out, int out_size, void* d_ws, size_t ws_size,
                              hipStream_t stream) {
    const float* a_feats  = (const float*)d_in[0];   // B*NA*64
    const float* b_feats  = (const float*)d_in[1];   // B*NB*64
    const int*   a_coords = (const int*)d_in[2];     // B*NA*3
    const int*   b_coords = (const int*)d_in[3];     // B*NB*3
    float* out = (float*)d_out;                      // B*NA*128

    const int B = in_sizes[0] / (NA * FD);
    dim3 grid(NA / WPB, B);
    knn_gather_kernel<<<grid, BLOCK, 0, stream>>>(a_feats, b_feats, a_coords,
                                                  b_coords, out);
}

// Round 2
// 107.939 us; speedup vs baseline: 1.3067x; 1.3067x over previous
//
#include <hip/hip_runtime.h>

// B=8, Na=Nb=4096, D=64. Top-3 NN by integer quantized coords (>>4, <128),
// weights 0.5-min(sqrt(d2)/128, 0.5), weighted gather of b_feats,
// out = [a_feats | gathered] (B,Na,128) fp32.
//
// Exact-integer selection: d2 = |ca-cb|^2 < 2^16 exact; fp32 sqrt monotone &
// injective on these ints -> reference top-k order == integer d2 order with
// low-index tie-break.
//
// key trick: rank by (d2 - |a|^2) instead of d2 (per-wave constant shift):
//   d2 - |a|^2 = |b|^2 - 2 a.b
//   G[i] = (|b_i|^2 << 12) | i          (staged in LDS once per block)
//   t    = a.b                           (one v_dot4_i32_i8)
//   key  = G - 8192*t = ((|b|^2-2t)<<12)|i   (one v_mad_i32_i24)
// signed-int min-3 of key == reference selection exactly (ties incl).
//
// Insert into sorted triple via med3 (3 ops):
//   k0'=min(k0,x); k1'=med3(k0,k1,x); k2'=med3(k1,k2,x)

#define NA 4096
#define NB 4096
#define FD 64
#define WPB 8                  // waves per block
#define MPW 8                  // a-points per wave
#define BLOCK (WPB * 64)
#define APB (WPB * MPW)        // 64 a-points per block

#if __has_builtin(__builtin_amdgcn_sdot4)
#define HAS_SDOT4 1
#else
#define HAS_SDOT4 0
#endif

static __device__ __forceinline__ int med3_i32(int a, int b, int c) {
    int d;
    asm("v_med3_i32 %0, %1, %2, %3" : "=v"(d) : "v"(a), "v"(b), "v"(c));
    return d;
}

__global__ __launch_bounds__(BLOCK, 4) void knn_gather_kernel(
    const float* __restrict__ a_feats,   // (B, NA, 64)
    const float* __restrict__ b_feats,   // (B, NB, 64)
    const int*   __restrict__ a_coords,  // (B, NA, 3)
    const int*   __restrict__ b_coords,  // (B, NB, 3)
    float* __restrict__ out)             // (B, NA, 128)
{
    __shared__ unsigned int s_pb[NB];    // packed bytes: x | y<<8 | z<<16
    __shared__ int          s_G[NB];     // (|b|^2 << 12) | idx

    const int batch = blockIdx.y;
    const int tid   = threadIdx.x;

    // ---- stage packed coords + G into LDS ----
    const int* bc = b_coords + (size_t)batch * NB * 3;
    for (int i = tid; i < NB; i += BLOCK) {
        const int x = bc[3 * i + 0] >> 4;
        const int y = bc[3 * i + 1] >> 4;
        const int z = bc[3 * i + 2] >> 4;
        s_pb[i] = (unsigned)(x | (y << 8) | (z << 16));
        s_G[i]  = ((__mul24(x, x) + __mul24(y, y) + __mul24(z, z)) << 12) | i;
    }
    __syncthreads();

    const int wave  = tid >> 6;
    const int lane  = tid & 63;
    const int nbase = blockIdx.x * APB + wave * MPW;

    // ---- per-wave a-point setup ----
    const int* ac = a_coords + ((size_t)batch * NA + nbase) * 3;
    int aa[MPW];                 // |a|^2 (epilogue only)
#if HAS_SDOT4
    int pa[MPW];                 // packed bytes of a
#else
    int axv[MPW], ayv[MPW], azv[MPW];
#endif
    int k0[MPW], k1[MPW], k2[MPW];
#pragma unroll
    for (int m = 0; m < MPW; ++m) {
        const int ax = ac[3 * m + 0] >> 4;
        const int ay = ac[3 * m + 1] >> 4;
        const int az = ac[3 * m + 2] >> 4;
        aa[m] = __mul24(ax, ax) + __mul24(ay, ay) + __mul24(az, az);
#if HAS_SDOT4
        pa[m] = ax | (ay << 8) | (az << 16);
#else
        axv[m] = ax; ayv[m] = ay; azv[m] = az;
#endif
        k0[m] = 0x7FFFFFFF; k1[m] = 0x7FFFFFFF; k2[m] = 0x7FFFFFFF;
    }

    // ---- hot loop: each lane scans 64 candidates (16 x uint4) ----
    const uint4* pb4 = (const uint4*)s_pb;
    const int4*  G4  = (const int4*)s_G;
#pragma unroll 2
    for (int k = 0; k < 16; ++k) {
        const int q = lane + (k << 6);
        const uint4 P = pb4[q];          // conflict-free: 16B * lane
        const int4  G = G4[q];
        const unsigned Pv[4] = {P.x, P.y, P.z, P.w};
        const int      Gv[4] = {G.x, G.y, G.z, G.w};
#pragma unroll
        for (int j = 0; j < 4; ++j) {
            const int Pj = (int)Pv[j];
            const int Gj = Gv[j];
#if !HAS_SDOT4
            const int bx = Pj & 255, by = (Pj >> 8) & 255, bz = (Pj >> 16) & 255;
#endif
#pragma unroll
            for (int m = 0; m < MPW; ++m) {
#if HAS_SDOT4
                const int t = __builtin_amdgcn_sdot4(pa[m], Pj, 0, false);
#else
                const int t = __mul24(axv[m], bx) + __mul24(ayv[m], by)
                            + __mul24(azv[m], bz);
#endif
                const int key = __mul24(t, -8192) + Gj;   // v_mad_i32_i24
                const int n0 = min(k0[m], key);
                const int n1 = med3_i32(k0[m], k1[m], key);
                const int n2 = med3_i32(k1[m], k2[m], key);
                k0[m] = n0; k1[m] = n1; k2[m] = n2;
            }
        }
    }

    // ---- per a-point: butterfly merge + weighted gather + store ----
    const float* bfb = b_feats + (size_t)batch * NB * FD;
#pragma unroll
    for (int m = 0; m < MPW; ++m) {
        int a0 = k0[m], a1 = k1[m], a2 = k2[m];
#pragma unroll
        for (int d = 1; d < 64; d <<= 1) {
            const int b0 = __shfl_xor(a0, d, 64);
            const int b1 = __shfl_xor(a1, d, 64);
            const int b2 = __shfl_xor(a2, d, 64);
            const int h0 = max(a0, b0);
            const int l1 = min(a1, b1);
            const int c2 = min(a2, b2);
            a0 = min(a0, b0);
            a1 = min(h0, l1);
            a2 = med3_i32(c2, l1, h0);   // = min(c2, max(l1,h0)), c2>=min(l1,h0)
        }
        // all lanes hold global sorted top-3 for a-point nbase+m
        const int i0 = a0 & 4095, i1 = a1 & 4095, i2 = a2 & 4095;
        const float d0 = sqrtf((float)((a0 >> 12) + aa[m])) * (1.0f / 128.0f);
        const float d1 = sqrtf((float)((a1 >> 12) + aa[m])) * (1.0f / 128.0f);
        const float d2 = sqrtf((float)((a2 >> 12) + aa[m])) * (1.0f / 128.0f);
        const float w0 = 0.5f - fminf(d0, 0.5f);
        const float w1 = 0.5f - fminf(d1, 0.5f);
        const float w2 = 0.5f - fminf(d2, 0.5f);

        const size_t row = (size_t)batch * NA + (nbase + m);
        const float g = w0 * bfb[i0 * FD + lane]
                      + w1 * bfb[i1 * FD + lane]
                      + w2 * bfb[i2 * FD + lane];
        out[row * 128 + lane]      = a_feats[row * FD + lane];
        out[row * 128 + 64 + lane] = g;
    }
}

extern "C" void kernel_launch(void* const* d_in, const int* in_sizes, int n_in,
                              void* d_out, int out_size, void* d_ws, size_t ws_size,
                              hipStream_t stream) {
    const float* a_feats  = (const float*)d_in[0];
    const float* b_feats  = (const float*)d_in[1];
    const int*   a_coords = (const int*)d_in[2];
    const int*   b_coords = (const int*)d_in[3];
    float* out = (float*)d_out;

    const int B = in_sizes[0] / (NA * FD);
    dim3 grid(NA / APB, B);
    knn_gather_kernel<<<grid, BLOCK, 0, stream>>>(a_feats, b_feats, a_coords,
                                                  b_coords, out);
}

// Round 3
// 101.969 us; speedup vs baseline: 1.3832x; 1.0586x over previous
//
#include <hip/hip_runtime.h>

// B=8, Na=Nb=4096, D=64. Top-3 NN by integer quantized coords (>>4, <128),
// weights 0.5-min(sqrt(d2)/128,0.5), weighted gather of b_feats,
// out = [a_feats | gathered] (B,Na,128) fp32.
//
// Exact-integer selection: d2 = |ca-cb|^2 < 2^16 exact; fp32 sqrt monotone &
// injective on these ints -> reference top-k order == integer d2 order with
// low-index tie-break.
//
// Rank by (d2 - |a|^2) = |b|^2 - 2 a.b (per-point constant shift):
//   G[i] = (|b_i|^2 << 12) | i     (LDS, built once per block)
//   t    = a.b                      (one v_dot4_i32_i8)
//   key  = -8192*t + G              (one v_mad_i32_i24)
// signed min-3 of key == reference selection exactly (ties -> lower idx,
// keys are globally unique since idx is embedded).
//
// Sorted-triple insert via med3 (3 ops):
//   k0'=min(k0,x); k1'=med3(k0,k1,x); k2'=med3(k1,k2,x)

#define NA 4096
#define NB 4096
#define FD 64
#define WPB 8                  // waves per block
#define MPW 4                  // a-points per wave (TLP over ILP: grid = 1024)
#define BLOCK (WPB * 64)
#define APB (WPB * MPW)        // 32 a-points per block

static __device__ __forceinline__ int med3_i32(int a, int b, int c) {
    int d;
    asm("v_med3_i32 %0, %1, %2, %3" : "=v"(d) : "v"(a), "v"(b), "v"(c));
    return d;
}

static __device__ __forceinline__ int mad_i24(int a, int b, int c) {
    int d;
    asm("v_mad_i32_i24 %0, %1, %2, %3" : "=v"(d) : "v"(a), "v"(b), "v"(c));
    return d;
}

__global__ __launch_bounds__(BLOCK, 8) void knn_gather_kernel(
    const float* __restrict__ a_feats,   // (B, NA, 64)
    const float* __restrict__ b_feats,   // (B, NB, 64)
    const int*   __restrict__ a_coords,  // (B, NA, 3)
    const int*   __restrict__ b_coords,  // (B, NB, 3)
    float* __restrict__ out)             // (B, NA, 128)
{
    __shared__ unsigned int s_pb[NB];    // packed bytes: x | y<<8 | z<<16
    __shared__ int          s_G[NB];     // (|b|^2 << 12) | idx

    const int batch = blockIdx.y;
    const int tid   = threadIdx.x;

    // ---- stage packed coords + G into LDS ----
    const int* bc = b_coords + (size_t)batch * NB * 3;
    for (int i = tid; i < NB; i += BLOCK) {
        const int x = bc[3 * i + 0] >> 4;
        const int y = bc[3 * i + 1] >> 4;
        const int z = bc[3 * i + 2] >> 4;
        s_pb[i] = (unsigned)(x | (y << 8) | (z << 16));
        s_G[i]  = ((__mul24(x, x) + __mul24(y, y) + __mul24(z, z)) << 12) | i;
    }
    __syncthreads();

    const int wave  = tid >> 6;
    const int lane  = tid & 63;
    const int nbase = blockIdx.x * APB + wave * MPW;

    // ---- per-wave a-point setup ----
    const int* ac = a_coords + ((size_t)batch * NA + nbase) * 3;
    int pa0, pa1, pa2, pa3;              // packed a coords (no arrays)
    {
        const int x0 = ac[0] >> 4, y0 = ac[1]  >> 4, z0 = ac[2]  >> 4;
        const int x1 = ac[3] >> 4, y1 = ac[4]  >> 4, z1 = ac[5]  >> 4;
        const int x2 = ac[6] >> 4, y2 = ac[7]  >> 4, z2 = ac[8]  >> 4;
        const int x3 = ac[9] >> 4, y3 = ac[10] >> 4, z3 = ac[11] >> 4;
        pa0 = x0 | (y0 << 8) | (z0 << 16);
        pa1 = x1 | (y1 << 8) | (z1 << 16);
        pa2 = x2 | (y2 << 8) | (z2 << 16);
        pa3 = x3 | (y3 << 8) | (z3 << 16);
    }
    const int neg8k = -8192;             // VOP3 can't take literal; keep in reg

    int k0_0 = 0x7FFFFFFF, k1_0 = 0x7FFFFFFF, k2_0 = 0x7FFFFFFF;
    int k0_1 = 0x7FFFFFFF, k1_1 = 0x7FFFFFFF, k2_1 = 0x7FFFFFFF;
    int k0_2 = 0x7FFFFFFF, k1_2 = 0x7FFFFFFF, k2_2 = 0x7FFFFFFF;
    int k0_3 = 0x7FFFFFFF, k1_3 = 0x7FFFFFFF, k2_3 = 0x7FFFFFFF;

    // ---- hot loop: each lane scans 64 candidates (16 x uint4), with
    //      rotating-register prefetch of the next pair of LDS vectors ----
    const uint4* pb4 = (const uint4*)s_pb;
    const int4*  G4  = (const int4*)s_G;
    uint4 P = pb4[lane];
    int4  G = G4[lane];

#define KNN_ONE(PJ, GJ)                                              \
    {                                                                \
        const int Pj = (int)(PJ);                                    \
        const int Gj = (GJ);                                         \
        {   const int t   = __builtin_amdgcn_sdot4(pa0, Pj, 0, false); \
            const int key = mad_i24(t, neg8k, Gj);                   \
            const int n0 = min(k0_0, key);                           \
            const int n1 = med3_i32(k0_0, k1_0, key);                \
            const int n2 = med3_i32(k1_0, k2_0, key);                \
            k0_0 = n0; k1_0 = n1; k2_0 = n2; }                       \
        {   const int t   = __builtin_amdgcn_sdot4(pa1, Pj, 0, false); \
            const int key = mad_i24(t, neg8k, Gj);                   \
            const int n0 = min(k0_1, key);                           \
            const int n1 = med3_i32(k0_1, k1_1, key);                \
            const int n2 = med3_i32(k1_1, k2_1, key);                \
            k0_1 = n0; k1_1 = n1; k2_1 = n2; }                       \
        {   const int t   = __builtin_amdgcn_sdot4(pa2, Pj, 0, false); \
            const int key = mad_i24(t, neg8k, Gj);                   \
            const int n0 = min(k0_2, key);                           \
            const int n1 = med3_i32(k0_2, k1_2, key);                \
            const int n2 = med3_i32(k1_2, k2_2, key);                \
            k0_2 = n0; k1_2 = n1; k2_2 = n2; }                       \
        {   const int t   = __builtin_amdgcn_sdot4(pa3, Pj, 0, false); \
            const int key = mad_i24(t, neg8k, Gj);                   \
            const int n0 = min(k0_3, key);                           \
            const int n1 = med3_i32(k0_3, k1_3, key);                \
            const int n2 = med3_i32(k1_3, k2_3, key);                \
            k0_3 = n0; k1_3 = n1; k2_3 = n2; }                       \
    }

#pragma unroll 2
    for (int k = 0; k < 16; ++k) {
        // prefetch next (k=15 reads into s_G region -- in-bounds garbage,
        // discarded)
        const int qn = lane + ((k + 1) << 6);
        const uint4 Pn = pb4[qn];
        const int4  Gn = G4[qn];

        KNN_ONE(P.x, G.x)
        KNN_ONE(P.y, G.y)
        KNN_ONE(P.z, G.z)
        KNN_ONE(P.w, G.w)

        P = Pn; G = Gn;
    }
#undef KNN_ONE

    // ---- per a-point: butterfly merge + weighted gather + store ----
    const float* bfb = b_feats + (size_t)batch * NB * FD;
    int K0[MPW] = {k0_0, k0_1, k0_2, k0_3};
    int K1[MPW] = {k1_0, k1_1, k1_2, k1_3};
    int K2[MPW] = {k2_0, k2_1, k2_2, k2_3};
    const int PA[MPW] = {pa0, pa1, pa2, pa3};

#pragma unroll
    for (int m = 0; m < MPW; ++m) {
        int a0 = K0[m], a1 = K1[m], a2 = K2[m];
#pragma unroll
        for (int d = 1; d < 64; d <<= 1) {
            const int b0 = __shfl_xor(a0, d, 64);
            const int b1 = __shfl_xor(a1, d, 64);
            const int b2 = __shfl_xor(a2, d, 64);
            const int h0 = max(a0, b0);
            const int l1 = min(a1, b1);
            const int c2 = min(a2, b2);
            a0 = min(a0, b0);
            a1 = min(h0, l1);
            a2 = med3_i32(c2, l1, h0);   // = min(c2, max(l1,h0))
        }
        const int aa = __builtin_amdgcn_sdot4(PA[m], PA[m], 0, false); // |a|^2
        const int i0 = a0 & 4095, i1 = a1 & 4095, i2 = a2 & 4095;
        const float d0 = sqrtf((float)((a0 >> 12) + aa)) * (1.0f / 128.0f);
        const float d1 = sqrtf((float)((a1 >> 12) + aa)) * (1.0f / 128.0f);
        const float d2 = sqrtf((float)((a2 >> 12) + aa)) * (1.0f / 128.0f);
        const float w0 = 0.5f - fminf(d0, 0.5f);
        const float w1 = 0.5f - fminf(d1, 0.5f);
        const float w2 = 0.5f - fminf(d2, 0.5f);

        const size_t row = (size_t)batch * NA + (nbase + m);
        const float g = w0 * bfb[i0 * FD + lane]
                      + w1 * bfb[i1 * FD + lane]
                      + w2 * bfb[i2 * FD + lane];
        out[row * 128 + lane]      = a_feats[row * FD + lane];
        out[row * 128 + 64 + lane] = g;
    }
}

extern "C" void kernel_launch(void* const* d_in, const int* in_sizes, int n_in,
                              void* d_out, int out_size, void* d_ws, size_t ws_size,
                              hipStream_t stream) {
    const float* a_feats  = (const float*)d_in[0];
    const float* b_feats  = (const float*)d_in[1];
    const int*   a_coords = (const int*)d_in[2];
    const int*   b_coords = (const int*)d_in[3];
    float* out = (float*)d_out;

    const int B = in_sizes[0] / (NA * FD);
    dim3 grid(NA / APB, B);
    knn_gather_kernel<<<grid, BLOCK, 0, stream>>>(a_feats, b_feats, a_coords,
                                                  b_coords, out);
}